// Round 13
// baseline (511.881 us; speedup 1.0000x reference)
//
#include <hip/hip_runtime.h>
#include <hip/hip_bf16.h>
#include <math.h>

#define T_TOK 8192
#define EMB   1024
#define HID   1536
#define NE    8

typedef float  floatx4 __attribute__((ext_vector_type(4)));
typedef __bf16 bf16x8  __attribute__((ext_vector_type(8)));

// ---- workspace layout (bytes) ----
#define WS_COUNTS   0
#define WS_TOKMAP   8192        // T*8*4
#define WS_TOKLIST  270336      // NE*T*4
#define WS_YBUF     532480      // ybuf 16384*1024*2; xbf aliases it (dead before gemm2 writes)
#define WS_W1T      34086912    // 25165824
#define WS_W2T      59252736    // 25165824
#define WS_H        84418560    // hbuf 16512 rows * 1536 * 2 (128-row pad for tail tiles)
#define WS_NEEDED   135143424

// wave-level dtype sniff (same exponent heuristic as the old sniff_kernel,
// 256-word cap). Every wave computes the same answer independently -> no
// shared mem, no barrier, no cross-kernel flags dependency.
__device__ __forceinline__ bool wave_sniff_f32(const void* p, int nelem) {
  const unsigned* w = (const unsigned*)p;
  int nw = nelem >> 1; if (nw > 256) nw = 256;
  const int lane = threadIdx.x & 63;
  int pl = 0, nz = 0;
  for (int i = lane; i < nw; i += 64) {
    unsigned v = w[i];
    if (v) { nz++; unsigned ex = (v >> 23) & 255; if (ex >= 100 && ex <= 150) pl++; }
  }
#pragma unroll
  for (int off = 32; off; off >>= 1) { pl += __shfl_xor(pl, off, 64); nz += __shfl_xor(nz, off, 64); }
  return 2 * pl > nz;
}

__device__ __forceinline__ float eload(const void* p, size_t idx, bool f32) {
  return f32 ? ((const float*)p)[idx] : (float)(((const __bf16*)p)[idx]);
}

// async global->LDS, 16B per lane; LDS dest = wave-uniform base + lane*16
__device__ __forceinline__ void glds16(const void* g, void* l) {
  __builtin_amdgcn_global_load_lds(
      (const __attribute__((address_space(1))) unsigned int*)g,
      (__attribute__((address_space(3))) unsigned int*)l, 16, 0, 0);
}

// =====================================================================
// prep_kernel: fused weight transposes + logits/top-k/x->bf16 + BINNING.
// Transpose role (blocks [0,1536)): LDS-free register 8x8 micro-tile
// transpose, one wave per 64x64 tile (unchanged from r11/r12).
// Logits role (blocks [1536,3584)): logits + top-k, then DIRECT binning
// via device-scope atomicAdd on counts[e]: pos = old count;
// tok_list[e][pos] = t; tokmap = (e<<16)|pos. Replaces bin_kernel.
// =====================================================================
__global__ __launch_bounds__(256)
void prep_kernel(const void* __restrict__ W1, const void* __restrict__ W2,
                 __bf16* __restrict__ w1t, __bf16* __restrict__ w2t,
                 const void* __restrict__ x, const void* __restrict__ Wr,
                 const void* __restrict__ br, const int* __restrict__ kptr,
                 int* __restrict__ tokmap, int* __restrict__ tok_list,
                 int* __restrict__ counts, __bf16* __restrict__ xbf) {
  const int bid = blockIdx.x;
  const int tid = threadIdx.x;
  const int wave = tid >> 6;
  const int lane = tid & 63;

  if (bid < 1536) {
    const void* in; __bf16* out; int K, N; int t;
    if (bid < 768) {
      in = W1; out = w1t; K = EMB; N = HID;
      t = bid * 4 + wave;                 // 0..3071
    } else {
      in = W2; out = w2t; K = HID; N = EMB;
      t = (bid - 768) * 4 + wave;         // 0..3071
    }
    const bool f32 = wave_sniff_f32(in, NE * EMB * HID);
    const int ntile = N / 64;             // W1:24, W2:16
    const int e  = t / 384;               // both: 384 tiles/expert
    const int r  = t % 384;
    const int kb = r / ntile;
    const int nb = r % ntile;
    const size_t eoff = (size_t)e * (size_t)K * (size_t)N;
    const int k0 = kb * 64 + (lane >> 3) * 8;   // this lane's 8 k-rows
    const int n0 = nb * 64 + (lane & 7) * 8;    // this lane's 8 n-cols

    if (f32) {
      floatx4 a0[8], a1[8];
#pragma unroll
      for (int i = 0; i < 8; ++i) {
        const float* g = (const float*)in + eoff + (size_t)(k0 + i) * N + n0;
        a0[i] = *(const floatx4*)g;
        a1[i] = *(const floatx4*)(g + 4);
      }
#pragma unroll
      for (int j = 0; j < 8; ++j) {
        bf16x8 o;
#pragma unroll
        for (int i = 0; i < 8; ++i)
          o[i] = (__bf16)(j < 4 ? a0[i][j] : a1[i][j - 4]);
        *(bf16x8*)(out + eoff + (size_t)(n0 + j) * K + k0) = o;
      }
    } else {
      bf16x8 a[8];
#pragma unroll
      for (int i = 0; i < 8; ++i)
        a[i] = *(const bf16x8*)((const __bf16*)in + eoff + (size_t)(k0 + i) * N + n0);
#pragma unroll
      for (int j = 0; j < 8; ++j) {
        bf16x8 o;
#pragma unroll
        for (int i = 0; i < 8; ++i) o[i] = a[i][j];
        *(bf16x8*)(out + eoff + (size_t)(n0 + j) * K + k0) = o;
      }
    }
    return;
  }

  // ---- logits + binning role ----
  const bool xf32  = wave_sniff_f32(x, T_TOK * EMB);
  const bool wrf32 = wave_sniff_f32(Wr, EMB * NE);
  const bool brf32 = wave_sniff_f32(br, NE);
  const int t = (bid - 1536) * 4 + wave;

  float xv[16];
  {
    size_t base = (size_t)t * EMB + lane * 16;
    if (xf32) {
      const float* g = (const float*)x + base;
#pragma unroll
      for (int c = 0; c < 4; ++c) {
        float4 v = *(const float4*)(g + c * 4);
        xv[c * 4 + 0] = v.x; xv[c * 4 + 1] = v.y; xv[c * 4 + 2] = v.z; xv[c * 4 + 3] = v.w;
      }
    } else {
      bf16x8 u = *(const bf16x8*)((const __bf16*)x + base);
      bf16x8 v = *(const bf16x8*)((const __bf16*)x + base + 8);
#pragma unroll
      for (int j = 0; j < 8; ++j) { xv[j] = (float)u[j]; xv[8 + j] = (float)v[j]; }
    }
  }
  {
    bf16x8 o0, o1;
#pragma unroll
    for (int j = 0; j < 8; ++j) { o0[j] = (__bf16)xv[j]; o1[j] = (__bf16)xv[8 + j]; }
    __bf16* xo = xbf + (size_t)t * EMB + lane * 16;
    *(bf16x8*)xo = o0;
    *(bf16x8*)(xo + 8) = o1;
  }
  float acc[NE];
#pragma unroll
  for (int e = 0; e < NE; ++e) acc[e] = 0.f;
  if (wrf32) {
#pragma unroll
    for (int j = 0; j < 16; ++j) {
      const float* wr = (const float*)Wr + (size_t)(lane * 16 + j) * NE;
#pragma unroll
      for (int e = 0; e < NE; ++e) acc[e] += xv[j] * wr[e];
    }
  } else {
#pragma unroll
    for (int j = 0; j < 16; ++j) {
      bf16x8 wr = *(const bf16x8*)((const __bf16*)Wr + (size_t)(lane * 16 + j) * NE);
#pragma unroll
      for (int e = 0; e < NE; ++e) acc[e] += xv[j] * (float)wr[e];
    }
  }
#pragma unroll
  for (int e = 0; e < NE; ++e) {
#pragma unroll
    for (int off = 32; off > 0; off >>= 1)
      acc[e] += __shfl_xor(acc[e], off, 64);
  }
  if (lane == 0) {
    int k = kptr[0];
    if (k < 1) k = 1; if (k > NE) k = NE;
    float lg[NE];
#pragma unroll
    for (int e = 0; e < NE; ++e) lg[e] = acc[e] + eload(br, e, brf32);
    for (int s = 0; s < k; ++s) {
      int bi = 0; float bv = lg[0];
#pragma unroll
      for (int e = 1; e < NE; ++e) { if (lg[e] > bv) { bv = lg[e]; bi = e; } }
      lg[bi] = -3.0e38f;
      int pos = atomicAdd(&counts[bi], 1);        // device-scope
      tok_list[bi * T_TOK + pos] = t;
      tokmap[t * 8 + s] = (bi << 16) | pos;
    }
  }
}

// =====================================================================
// m97-structure grouped GEMM, BK=64 (K-loop byte-identical to r8-r12):
// 128x128 tile, 256 threads = 4 waves, 32KB LDS, 2 barriers/K-step.
// Swizzle: LDS[R][c] holds global chunk c^(R&7); reads use (s*4+fc)^(R&7).
// offsets computed in-register from counts (8 predicated adds).
// tok_list pad handled by clamping the index to cnt-1 (no pad-zeroing).
// =====================================================================

// ---------------- GEMM1: h = gelu(x_gather @ W1[e] + b1[e]) ----------------
__global__ __launch_bounds__(256, 4)
void gemm1_kernel(const __bf16* __restrict__ xbf, const __bf16* __restrict__ w1t,
                  const void* __restrict__ b1, const int* __restrict__ counts,
                  const int* __restrict__ tok_list, __bf16* __restrict__ hbuf) {
  const int flat = blockIdx.x;
  const int e   = flat & 7;              // expert -> XCD pin
  const int idx = flat >> 3;             // 0..191
  const int g   = idx / 12;              // 0..15 (mT stride group)
  const int nT  = idx % 12;              // 0..11
  int cnt = 0, off_e = 0;
#pragma unroll
  for (int i = 0; i < NE; ++i) { int c = counts[i]; if (i < e) off_e += c; if (i == e) cnt = c; }
  const bool b1f32 = wave_sniff_f32(b1, NE * HID);

  __shared__ __align__(16) __bf16 As[128 * 64];
  __shared__ __align__(16) __bf16 Bs[128 * 64];

  const int wave = threadIdx.x >> 6;
  const int lane = threadIdx.x & 63;
  const int lrow = lane >> 3;            // 0..7
  const int cgs  = (lane & 7) ^ lrow;    // swizzled source chunk

  int Rst[4];
#pragma unroll
  for (int q = 0; q < 4; ++q) Rst[q] = (q * 4 + wave) * 8 + lrow;

  const __bf16* pB[4];
#pragma unroll
  for (int q = 0; q < 4; ++q)
    pB[q] = w1t + ((size_t)e * HID + nT * 128 + Rst[q]) * EMB + cgs * 8;

  const int wm = (wave & 1) * 64;
  const int wn = (wave >> 1) * 64;
  const int fr = lane & 15;
  const int fc = lane >> 4;
  int aOff0[4], aOff1[4], bOff0[4], bOff1[4];
#pragma unroll
  for (int i = 0; i < 4; ++i) {
    int R = wm + i * 16 + fr;
    aOff0[i] = R * 128 + (((fc)     ^ (R & 7)) << 4);
    aOff1[i] = R * 128 + (((fc + 4) ^ (R & 7)) << 4);
  }
#pragma unroll
  for (int j = 0; j < 4; ++j) {
    int R = wn + j * 16 + fr;
    bOff0[j] = R * 128 + (((fc)     ^ (R & 7)) << 4);
    bOff1[j] = R * 128 + (((fc + 4) ^ (R & 7)) << 4);
  }

  const int colBase = nT * 128 + wn + fr;
  float bv[4];
#pragma unroll
  for (int j = 0; j < 4; ++j) bv[j] = eload(b1, (size_t)e * HID + colBase + j * 16, b1f32);

  for (int mT = g; mT * 128 < cnt; mT += 16) {
    const __bf16* pA[4];
#pragma unroll
    for (int q = 0; q < 4; ++q) {
      int idxr = mT * 128 + Rst[q];
      if (idxr > cnt - 1) idxr = cnt - 1;               // clamp: pad rows re-read last valid token
      const int tok = tok_list[e * T_TOK + idxr];
      pA[q] = xbf + (size_t)tok * EMB + cgs * 8;
    }

    floatx4 acc[4][4];
#pragma unroll
    for (int i = 0; i < 4; ++i)
#pragma unroll
      for (int j = 0; j < 4; ++j) acc[i][j] = (floatx4){0.f, 0.f, 0.f, 0.f};

    for (int kb = 0; kb < EMB / 64; ++kb) {
      __syncthreads();
#pragma unroll
      for (int q = 0; q < 4; ++q) glds16(pA[q] + (size_t)kb * 64, As + (q * 4 + wave) * 512);
#pragma unroll
      for (int q = 0; q < 4; ++q) glds16(pB[q] + (size_t)kb * 64, Bs + (q * 4 + wave) * 512);
      __syncthreads();
      bf16x8 af[4], bfr[4];
#pragma unroll
      for (int i = 0; i < 4; ++i) af[i]  = *(const bf16x8*)((const char*)As + aOff0[i]);
#pragma unroll
      for (int j = 0; j < 4; ++j) bfr[j] = *(const bf16x8*)((const char*)Bs + bOff0[j]);
#pragma unroll
      for (int i = 0; i < 4; ++i)
#pragma unroll
        for (int j = 0; j < 4; ++j)
          acc[i][j] = __builtin_amdgcn_mfma_f32_16x16x32_bf16(af[i], bfr[j], acc[i][j], 0, 0, 0);
#pragma unroll
      for (int i = 0; i < 4; ++i) af[i]  = *(const bf16x8*)((const char*)As + aOff1[i]);
#pragma unroll
      for (int j = 0; j < 4; ++j) bfr[j] = *(const bf16x8*)((const char*)Bs + bOff1[j]);
#pragma unroll
      for (int i = 0; i < 4; ++i)
#pragma unroll
        for (int j = 0; j < 4; ++j)
          acc[i][j] = __builtin_amdgcn_mfma_f32_16x16x32_bf16(af[i], bfr[j], acc[i][j], 0, 0, 0);
    }

    const int hBase = off_e + mT * 128;
#pragma unroll
    for (int i = 0; i < 4; ++i) {
      const int rowLoc = wm + i * 16 + fc * 4;
#pragma unroll
      for (int r = 0; r < 4; ++r) {
        const int row = rowLoc + r;
        if (mT * 128 + row < cnt) {
          __bf16* hp = hbuf + (size_t)(hBase + row) * HID + colBase;
#pragma unroll
          for (int j = 0; j < 4; ++j) {
            float v = acc[i][j][r] + bv[j];
            float gl = 0.5f * v * (1.0f + erff(v * 0.70710678118654752f));
            hp[j * 16] = (__bf16)gl;
          }
        }
      }
    }
  }
}

// ---------------- GEMM2: ybuf[row] = h @ W2[e] + b2[e] ----------------
__global__ __launch_bounds__(256, 4)
void gemm2_kernel(const __bf16* __restrict__ hbuf, const __bf16* __restrict__ w2t,
                  const void* __restrict__ b2, const int* __restrict__ counts,
                  __bf16* __restrict__ ybuf) {
  const int flat = blockIdx.x;
  const int e   = flat & 7;
  const int idx = flat >> 3;             // 0..127
  const int g   = idx >> 3;              // 0..15
  const int nT  = idx & 7;               // 0..7
  int cnt = 0, off_e = 0;
#pragma unroll
  for (int i = 0; i < NE; ++i) { int c = counts[i]; if (i < e) off_e += c; if (i == e) cnt = c; }
  const bool b2f32 = wave_sniff_f32(b2, NE * EMB);

  __shared__ __align__(16) __bf16 As[128 * 64];
  __shared__ __align__(16) __bf16 Bs[128 * 64];

  const int wave = threadIdx.x >> 6;
  const int lane = threadIdx.x & 63;
  const int lrow = lane >> 3;
  const int cgs  = (lane & 7) ^ lrow;

  int Rst[4];
#pragma unroll
  for (int q = 0; q < 4; ++q) Rst[q] = (q * 4 + wave) * 8 + lrow;

  const __bf16* pB[4];
#pragma unroll
  for (int q = 0; q < 4; ++q)
    pB[q] = w2t + ((size_t)e * EMB + nT * 128 + Rst[q]) * HID + cgs * 8;

  const int wm = (wave & 1) * 64;
  const int wn = (wave >> 1) * 64;
  const int fr = lane & 15;
  const int fc = lane >> 4;
  int aOff0[4], aOff1[4], bOff0[4], bOff1[4];
#pragma unroll
  for (int i = 0; i < 4; ++i) {
    int R = wm + i * 16 + fr;
    aOff0[i] = R * 128 + (((fc)     ^ (R & 7)) << 4);
    aOff1[i] = R * 128 + (((fc + 4) ^ (R & 7)) << 4);
  }
#pragma unroll
  for (int j = 0; j < 4; ++j) {
    int R = wn + j * 16 + fr;
    bOff0[j] = R * 128 + (((fc)     ^ (R & 7)) << 4);
    bOff1[j] = R * 128 + (((fc + 4) ^ (R & 7)) << 4);
  }

  const int colBase = nT * 128 + wn + fr;
  float bv[4];
#pragma unroll
  for (int j = 0; j < 4; ++j) bv[j] = eload(b2, (size_t)e * EMB + colBase + j * 16, b2f32);

  for (int mT = g; mT * 128 < cnt; mT += 16) {
    const int rowBase = off_e + mT * 128;
    const __bf16* pA[4];
#pragma unroll
    for (int q = 0; q < 4; ++q)
      pA[q] = hbuf + (size_t)(rowBase + Rst[q]) * HID + cgs * 8;

    floatx4 acc[4][4];
#pragma unroll
    for (int i = 0; i < 4; ++i)
#pragma unroll
      for (int j = 0; j < 4; ++j) acc[i][j] = (floatx4){0.f, 0.f, 0.f, 0.f};

    for (int kb = 0; kb < HID / 64; ++kb) {
      __syncthreads();
#pragma unroll
      for (int q = 0; q < 4; ++q) glds16(pA[q] + (size_t)kb * 64, As + (q * 4 + wave) * 512);
#pragma unroll
      for (int q = 0; q < 4; ++q) glds16(pB[q] + (size_t)kb * 64, Bs + (q * 4 + wave) * 512);
      __syncthreads();
      bf16x8 af[4], bfr[4];
#pragma unroll
      for (int i = 0; i < 4; ++i) af[i]  = *(const bf16x8*)((const char*)As + aOff0[i]);
#pragma unroll
      for (int j = 0; j < 4; ++j) bfr[j] = *(const bf16x8*)((const char*)Bs + bOff0[j]);
#pragma unroll
      for (int i = 0; i < 4; ++i)
#pragma unroll
        for (int j = 0; j < 4; ++j)
          acc[i][j] = __builtin_amdgcn_mfma_f32_16x16x32_bf16(af[i], bfr[j], acc[i][j], 0, 0, 0);
#pragma unroll
      for (int i = 0; i < 4; ++i) af[i]  = *(const bf16x8*)((const char*)As + aOff1[i]);
#pragma unroll
      for (int j = 0; j < 4; ++j) bfr[j] = *(const bf16x8*)((const char*)Bs + bOff1[j]);
#pragma unroll
      for (int i = 0; i < 4; ++i)
#pragma unroll
        for (int j = 0; j < 4; ++j)
          acc[i][j] = __builtin_amdgcn_mfma_f32_16x16x32_bf16(af[i], bfr[j], acc[i][j], 0, 0, 0);
    }

#pragma unroll
    for (int i = 0; i < 4; ++i) {
      const int rowLoc = wm + i * 16 + fc * 4;
#pragma unroll
      for (int r = 0; r < 4; ++r) {
        const int row = rowLoc + r;
        if (mT * 128 + row < cnt) {
          __bf16* yp = ybuf + (size_t)(rowBase + row) * EMB + colBase;
#pragma unroll
          for (int j = 0; j < 4; ++j)
            yp[j * 16] = (__bf16)(acc[i][j][r] + bv[j]);
        }
      }
    }
  }
}

// ---------------- combine: out[t] = (sum_s ybuf[off(e)+pos]) / k ----------------
__global__ __launch_bounds__(256)
void combine_kernel(const __bf16* __restrict__ ybuf, const int* __restrict__ tokmap,
                    const int* __restrict__ counts, const int* __restrict__ kptr,
                    const void* __restrict__ x, void* __restrict__ out) {
  const bool f32 = wave_sniff_f32(x, T_TOK * EMB);   // out dtype == x dtype
  const int wave = threadIdx.x >> 6;
  const int lane = threadIdx.x & 63;
  const int t = blockIdx.x * 4 + wave;
  int k = kptr[0];
  if (k < 1) k = 1; if (k > NE) k = NE;
  const float invk = 1.0f / (float)k;
  int cArr[NE];
#pragma unroll
  for (int i = 0; i < NE; ++i) cArr[i] = counts[i];
  int rows[NE];
  for (int s = 0; s < k; ++s) {
    int m = tokmap[t * 8 + s];
    int es = (m >> 16) & 7;
    int off = 0;
#pragma unroll
    for (int i = 0; i < NE; ++i) if (i < es) off += cArr[i];
    rows[s] = off + (m & 0xFFFF);
  }
#pragma unroll
  for (int c = 0; c < 2; ++c) {
    const int i = c * 512 + lane * 8;
    float a[8];
#pragma unroll
    for (int j = 0; j < 8; ++j) a[j] = 0.f;
    for (int s = 0; s < k; ++s) {
      bf16x8 y = *(const bf16x8*)(ybuf + (size_t)rows[s] * EMB + i);
#pragma unroll
      for (int j = 0; j < 8; ++j) a[j] += (float)y[j];
    }
    if (f32) {
      float* op = (float*)out + (size_t)t * EMB + i;
      float4 u = {a[0] * invk, a[1] * invk, a[2] * invk, a[3] * invk};
      float4 v = {a[4] * invk, a[5] * invk, a[6] * invk, a[7] * invk};
      *(float4*)op = u;
      *(float4*)(op + 4) = v;
    } else {
      bf16x8 o;
#pragma unroll
      for (int j = 0; j < 8; ++j) o[j] = (__bf16)(a[j] * invk);
      *(bf16x8*)((__bf16*)out + (size_t)t * EMB + i) = o;
    }
  }
}

extern "C" void kernel_launch(void* const* d_in, const int* in_sizes, int n_in,
                              void* d_out, int out_size, void* d_ws, size_t ws_size,
                              hipStream_t stream) {
  (void)in_sizes; (void)n_in; (void)out_size;
  if (ws_size < (size_t)WS_NEEDED) return;

  const void* x  = d_in[0];
  const void* Wr = d_in[1];
  const void* br = d_in[2];
  const void* W1 = d_in[3];
  const void* b1 = d_in[4];
  const void* W2 = d_in[5];
  const void* b2 = d_in[6];
  const int* kptr = (const int*)d_in[7];

  char* ws = (char*)d_ws;
  int*    counts   = (int*)(ws + WS_COUNTS);
  int*    tokmap   = (int*)(ws + WS_TOKMAP);
  int*    tok_list = (int*)(ws + WS_TOKLIST);
  __bf16* ybuf     = (__bf16*)(ws + WS_YBUF);
  __bf16* xbf      = (__bf16*)(ws + WS_YBUF);   // aliases ybuf; dead before gemm2 writes
  __bf16* w1t      = (__bf16*)(ws + WS_W1T);
  __bf16* w2t      = (__bf16*)(ws + WS_W2T);
  __bf16* hbuf     = (__bf16*)(ws + WS_H);

  hipMemsetAsync(counts, 0, NE * sizeof(int), stream);

  prep_kernel<<<dim3(1536 + T_TOK / 4), 256, 0, stream>>>(
      W1, W2, w1t, w2t, x, Wr, br, kptr, tokmap, tok_list, counts, xbf);

  gemm1_kernel<<<dim3(8 * 16 * 12), 256, 0, stream>>>(
      xbf, w1t, b1, counts, tok_list, hbuf);
  gemm2_kernel<<<dim3(8 * 16 * 8), 256, 0, stream>>>(
      hbuf, w2t, b2, counts, ybuf);

  combine_kernel<<<dim3(T_TOK / 4), 256, 0, stream>>>(ybuf, tokmap, counts, kptr, x, d_out);
}

// Round 14
// 378.396 us; speedup vs baseline: 1.3528x; 1.3528x over previous
//
#include <hip/hip_runtime.h>
#include <hip/hip_bf16.h>
#include <math.h>

#define T_TOK 8192
#define EMB   1024
#define HID   1536
#define NE    8

typedef float  floatx4 __attribute__((ext_vector_type(4)));
typedef __bf16 bf16x8  __attribute__((ext_vector_type(8)));

// ---- workspace layout (bytes) ----
#define WS_COUNTS   0
#define WS_OFFSETS  1024
#define WS_TOKMAP   8192        // T*8*4
#define WS_TOKLIST  270336      // NE*T*4
#define WS_YBUF     532480      // ybuf 16384*1024*2; xbf aliases it (dead before gemm2 writes)
#define WS_W1T      34086912    // 25165824
#define WS_W2T      59252736    // 25165824
#define WS_H        84418560    // hbuf 16512 rows * 1536 * 2 (128-row pad for tail tiles)
#define WS_NEEDED   135143424

// wave-level dtype sniff (256-word cap; all waves compute the same answer).
// Cheap: 4 L2-hit loads + 12 shuffles per wave; no barrier, no flags dep.
__device__ __forceinline__ bool wave_sniff_f32(const void* p, int nelem) {
  const unsigned* w = (const unsigned*)p;
  int nw = nelem >> 1; if (nw > 256) nw = 256;
  const int lane = threadIdx.x & 63;
  int pl = 0, nz = 0;
  for (int i = lane; i < nw; i += 64) {
    unsigned v = w[i];
    if (v) { nz++; unsigned ex = (v >> 23) & 255; if (ex >= 100 && ex <= 150) pl++; }
  }
#pragma unroll
  for (int off = 32; off; off >>= 1) { pl += __shfl_xor(pl, off, 64); nz += __shfl_xor(nz, off, 64); }
  return 2 * pl > nz;
}

__device__ __forceinline__ float eload(const void* p, size_t idx, bool f32) {
  return f32 ? ((const float*)p)[idx] : (float)(((const __bf16*)p)[idx]);
}

// async global->LDS, 16B per lane; LDS dest = wave-uniform base + lane*16
__device__ __forceinline__ void glds16(const void* g, void* l) {
  __builtin_amdgcn_global_load_lds(
      (const __attribute__((address_space(1))) unsigned int*)g,
      (__attribute__((address_space(3))) unsigned int*)l, 16, 0, 0);
}

// =====================================================================
// prep_kernel: fused weight transposes + logits/top-k/x->bf16.
// Transpose role (blocks [0,1536)): LDS-free register 8x8 micro-tile
// transpose, one wave per 64x64 tile (r11/r12 structure, measured fast).
// Logits role (blocks [1536,3584)): logits + top-k -> tokmap slots hold
// raw expert ids. NO global atomics here (r13 lesson: 16K device-scope
// RMWs on 8 words serialized ~210us; binning belongs in LDS -> bin_kernel).
// =====================================================================
__global__ __launch_bounds__(256)
void prep_kernel(const void* __restrict__ W1, const void* __restrict__ W2,
                 __bf16* __restrict__ w1t, __bf16* __restrict__ w2t,
                 const void* __restrict__ x, const void* __restrict__ Wr,
                 const void* __restrict__ br, const int* __restrict__ kptr,
                 int* __restrict__ tokmap, __bf16* __restrict__ xbf) {
  const int bid = blockIdx.x;
  const int tid = threadIdx.x;
  const int wave = tid >> 6;
  const int lane = tid & 63;

  if (bid < 1536) {
    const void* in; __bf16* out; int K, N; int t;
    if (bid < 768) {
      in = W1; out = w1t; K = EMB; N = HID;
      t = bid * 4 + wave;                 // 0..3071
    } else {
      in = W2; out = w2t; K = HID; N = EMB;
      t = (bid - 768) * 4 + wave;         // 0..3071
    }
    const bool f32 = wave_sniff_f32(in, NE * EMB * HID);
    const int ntile = N / 64;             // W1:24, W2:16
    const int e  = t / 384;               // both: 384 tiles/expert
    const int r  = t % 384;
    const int kb = r / ntile;
    const int nb = r % ntile;
    const size_t eoff = (size_t)e * (size_t)K * (size_t)N;
    const int k0 = kb * 64 + (lane >> 3) * 8;   // this lane's 8 k-rows
    const int n0 = nb * 64 + (lane & 7) * 8;    // this lane's 8 n-cols

    if (f32) {
      floatx4 a0[8], a1[8];
#pragma unroll
      for (int i = 0; i < 8; ++i) {
        const float* g = (const float*)in + eoff + (size_t)(k0 + i) * N + n0;
        a0[i] = *(const floatx4*)g;
        a1[i] = *(const floatx4*)(g + 4);
      }
#pragma unroll
      for (int j = 0; j < 8; ++j) {
        bf16x8 o;
#pragma unroll
        for (int i = 0; i < 8; ++i)
          o[i] = (__bf16)(j < 4 ? a0[i][j] : a1[i][j - 4]);
        *(bf16x8*)(out + eoff + (size_t)(n0 + j) * K + k0) = o;
      }
    } else {
      bf16x8 a[8];
#pragma unroll
      for (int i = 0; i < 8; ++i)
        a[i] = *(const bf16x8*)((const __bf16*)in + eoff + (size_t)(k0 + i) * N + n0);
#pragma unroll
      for (int j = 0; j < 8; ++j) {
        bf16x8 o;
#pragma unroll
        for (int i = 0; i < 8; ++i) o[i] = a[i][j];
        *(bf16x8*)(out + eoff + (size_t)(n0 + j) * K + k0) = o;
      }
    }
    return;
  }

  // ---- logits role ----
  const bool xf32  = wave_sniff_f32(x, T_TOK * EMB);
  const bool wrf32 = wave_sniff_f32(Wr, EMB * NE);
  const bool brf32 = wave_sniff_f32(br, NE);
  const int t = (bid - 1536) * 4 + wave;

  float xv[16];
  {
    size_t base = (size_t)t * EMB + lane * 16;
    if (xf32) {
      const float* g = (const float*)x + base;
#pragma unroll
      for (int c = 0; c < 4; ++c) {
        float4 v = *(const float4*)(g + c * 4);
        xv[c * 4 + 0] = v.x; xv[c * 4 + 1] = v.y; xv[c * 4 + 2] = v.z; xv[c * 4 + 3] = v.w;
      }
    } else {
      bf16x8 u = *(const bf16x8*)((const __bf16*)x + base);
      bf16x8 v = *(const bf16x8*)((const __bf16*)x + base + 8);
#pragma unroll
      for (int j = 0; j < 8; ++j) { xv[j] = (float)u[j]; xv[8 + j] = (float)v[j]; }
    }
  }
  {
    bf16x8 o0, o1;
#pragma unroll
    for (int j = 0; j < 8; ++j) { o0[j] = (__bf16)xv[j]; o1[j] = (__bf16)xv[8 + j]; }
    __bf16* xo = xbf + (size_t)t * EMB + lane * 16;
    *(bf16x8*)xo = o0;
    *(bf16x8*)(xo + 8) = o1;
  }
  float acc[NE];
#pragma unroll
  for (int e = 0; e < NE; ++e) acc[e] = 0.f;
  if (wrf32) {
#pragma unroll
    for (int j = 0; j < 16; ++j) {
      const float* wr = (const float*)Wr + (size_t)(lane * 16 + j) * NE;
#pragma unroll
      for (int e = 0; e < NE; ++e) acc[e] += xv[j] * wr[e];
    }
  } else {
#pragma unroll
    for (int j = 0; j < 16; ++j) {
      bf16x8 wr = *(const bf16x8*)((const __bf16*)Wr + (size_t)(lane * 16 + j) * NE);
#pragma unroll
      for (int e = 0; e < NE; ++e) acc[e] += xv[j] * (float)wr[e];
    }
  }
#pragma unroll
  for (int e = 0; e < NE; ++e) {
#pragma unroll
    for (int off = 32; off > 0; off >>= 1)
      acc[e] += __shfl_xor(acc[e], off, 64);
  }
  if (lane == 0) {
    int k = kptr[0];
    if (k < 1) k = 1; if (k > NE) k = NE;
    float lg[NE];
#pragma unroll
    for (int e = 0; e < NE; ++e) lg[e] = acc[e] + eload(br, e, brf32);
    for (int s = 0; s < k; ++s) {
      int bi = 0; float bv = lg[0];
#pragma unroll
      for (int e = 1; e < NE; ++e) { if (lg[e] > bv) { bv = lg[e]; bi = e; } }
      lg[bi] = -3.0e38f;
      tokmap[t * 8 + s] = bi;
    }
  }
}

// =====================================================================
// bin_kernel: single block, 1024 threads, LDS atomics (r10 structure,
// measured ~10us). pos assignment -> tok_list/tokmap; scan -> counts/
// offsets; zero the 128-row tok_list pads.
// =====================================================================
__global__ __launch_bounds__(1024)
void bin_kernel(const int* __restrict__ kptr, int* __restrict__ tokmap,
                int* __restrict__ tok_list, int* __restrict__ counts,
                int* __restrict__ offsets) {
  __shared__ int lcnt[NE];
  __shared__ int soff[NE + 1];
  const int tid = threadIdx.x;
  if (tid < NE) lcnt[tid] = 0;
  __syncthreads();
  int k = kptr[0];
  if (k < 1) k = 1; if (k > NE) k = NE;
  for (int t = tid; t < T_TOK; t += 1024) {
    for (int s = 0; s < k; ++s) {
      int e = tokmap[t * 8 + s] & 7;
      int pos = atomicAdd(&lcnt[e], 1);
      tok_list[e * T_TOK + pos] = t;
      tokmap[t * 8 + s] = (e << 16) | pos;
    }
  }
  __syncthreads();
  if (tid == 0) {
    int s = 0;
    for (int e = 0; e < NE; ++e) { soff[e] = s; s += lcnt[e]; }
    soff[NE] = s;
  }
  __syncthreads();
  if (tid < NE) counts[tid] = lcnt[tid];
  if (tid <= NE) offsets[tid] = soff[tid];
  for (int e = 0; e < NE; ++e) {
    const int c = lcnt[e];
    const int end = (c + 127) & ~127;
    for (int i = c + tid; i < end; i += 1024) tok_list[e * T_TOK + i] = 0;
  }
}

// =====================================================================
// m97-structure grouped GEMM, BK=64 (K-loop byte-identical to r8-r12):
// 128x128 tile, 256 threads = 4 waves, 32KB LDS, 2 barriers/K-step.
// Swizzle: LDS[R][c] holds global chunk c^(R&7); reads use (s*4+fc)^(R&7).
// =====================================================================

// ---------------- GEMM1: h = gelu(x_gather @ W1[e] + b1[e]) ----------------
__global__ __launch_bounds__(256, 4)
void gemm1_kernel(const __bf16* __restrict__ xbf, const __bf16* __restrict__ w1t,
                  const void* __restrict__ b1, const int* __restrict__ counts,
                  const int* __restrict__ offsets, const int* __restrict__ tok_list,
                  __bf16* __restrict__ hbuf) {
  const int flat = blockIdx.x;
  const int e   = flat & 7;              // expert -> XCD pin
  const int idx = flat >> 3;             // 0..191
  const int g   = idx / 12;              // 0..15 (mT stride group)
  const int nT  = idx % 12;              // 0..11
  const int cnt = counts[e];
  const bool b1f32 = wave_sniff_f32(b1, NE * HID);

  __shared__ __align__(16) __bf16 As[128 * 64];
  __shared__ __align__(16) __bf16 Bs[128 * 64];

  const int wave = threadIdx.x >> 6;
  const int lane = threadIdx.x & 63;
  const int lrow = lane >> 3;            // 0..7
  const int cgs  = (lane & 7) ^ lrow;    // swizzled source chunk

  int Rst[4];
#pragma unroll
  for (int q = 0; q < 4; ++q) Rst[q] = (q * 4 + wave) * 8 + lrow;

  const __bf16* pB[4];
#pragma unroll
  for (int q = 0; q < 4; ++q)
    pB[q] = w1t + ((size_t)e * HID + nT * 128 + Rst[q]) * EMB + cgs * 8;

  const int wm = (wave & 1) * 64;
  const int wn = (wave >> 1) * 64;
  const int fr = lane & 15;
  const int fc = lane >> 4;
  int aOff0[4], aOff1[4], bOff0[4], bOff1[4];
#pragma unroll
  for (int i = 0; i < 4; ++i) {
    int R = wm + i * 16 + fr;
    aOff0[i] = R * 128 + (((fc)     ^ (R & 7)) << 4);
    aOff1[i] = R * 128 + (((fc + 4) ^ (R & 7)) << 4);
  }
#pragma unroll
  for (int j = 0; j < 4; ++j) {
    int R = wn + j * 16 + fr;
    bOff0[j] = R * 128 + (((fc)     ^ (R & 7)) << 4);
    bOff1[j] = R * 128 + (((fc + 4) ^ (R & 7)) << 4);
  }

  const int colBase = nT * 128 + wn + fr;
  float bv[4];
#pragma unroll
  for (int j = 0; j < 4; ++j) bv[j] = eload(b1, (size_t)e * HID + colBase + j * 16, b1f32);

  for (int mT = g; mT * 128 < cnt; mT += 16) {
    const __bf16* pA[4];
#pragma unroll
    for (int q = 0; q < 4; ++q) {
      const int tok = tok_list[e * T_TOK + mT * 128 + Rst[q]];  // pad entries = 0
      pA[q] = xbf + (size_t)tok * EMB + cgs * 8;
    }

    floatx4 acc[4][4];
#pragma unroll
    for (int i = 0; i < 4; ++i)
#pragma unroll
      for (int j = 0; j < 4; ++j) acc[i][j] = (floatx4){0.f, 0.f, 0.f, 0.f};

    for (int kb = 0; kb < EMB / 64; ++kb) {
      __syncthreads();
#pragma unroll
      for (int q = 0; q < 4; ++q) glds16(pA[q] + (size_t)kb * 64, As + (q * 4 + wave) * 512);
#pragma unroll
      for (int q = 0; q < 4; ++q) glds16(pB[q] + (size_t)kb * 64, Bs + (q * 4 + wave) * 512);
      __syncthreads();
      bf16x8 af[4], bfr[4];
#pragma unroll
      for (int i = 0; i < 4; ++i) af[i]  = *(const bf16x8*)((const char*)As + aOff0[i]);
#pragma unroll
      for (int j = 0; j < 4; ++j) bfr[j] = *(const bf16x8*)((const char*)Bs + bOff0[j]);
#pragma unroll
      for (int i = 0; i < 4; ++i)
#pragma unroll
        for (int j = 0; j < 4; ++j)
          acc[i][j] = __builtin_amdgcn_mfma_f32_16x16x32_bf16(af[i], bfr[j], acc[i][j], 0, 0, 0);
#pragma unroll
      for (int i = 0; i < 4; ++i) af[i]  = *(const bf16x8*)((const char*)As + aOff1[i]);
#pragma unroll
      for (int j = 0; j < 4; ++j) bfr[j] = *(const bf16x8*)((const char*)Bs + bOff1[j]);
#pragma unroll
      for (int i = 0; i < 4; ++i)
#pragma unroll
        for (int j = 0; j < 4; ++j)
          acc[i][j] = __builtin_amdgcn_mfma_f32_16x16x32_bf16(af[i], bfr[j], acc[i][j], 0, 0, 0);
    }

    const int hBase = offsets[e] + mT * 128;
#pragma unroll
    for (int i = 0; i < 4; ++i) {
      const int rowLoc = wm + i * 16 + fc * 4;
#pragma unroll
      for (int r = 0; r < 4; ++r) {
        const int row = rowLoc + r;
        if (mT * 128 + row < cnt) {
          __bf16* hp = hbuf + (size_t)(hBase + row) * HID + colBase;
#pragma unroll
          for (int j = 0; j < 4; ++j) {
            float v = acc[i][j][r] + bv[j];
            float gl = 0.5f * v * (1.0f + erff(v * 0.70710678118654752f));
            hp[j * 16] = (__bf16)gl;
          }
        }
      }
    }
  }
}

// ---------------- GEMM2: ybuf[row] = h @ W2[e] + b2[e] ----------------
__global__ __launch_bounds__(256, 4)
void gemm2_kernel(const __bf16* __restrict__ hbuf, const __bf16* __restrict__ w2t,
                  const void* __restrict__ b2, const int* __restrict__ counts,
                  const int* __restrict__ offsets, __bf16* __restrict__ ybuf) {
  const int flat = blockIdx.x;
  const int e   = flat & 7;
  const int idx = flat >> 3;             // 0..127
  const int g   = idx >> 3;              // 0..15
  const int nT  = idx & 7;               // 0..7
  const int cnt = counts[e];
  const bool b2f32 = wave_sniff_f32(b2, NE * EMB);

  __shared__ __align__(16) __bf16 As[128 * 64];
  __shared__ __align__(16) __bf16 Bs[128 * 64];

  const int wave = threadIdx.x >> 6;
  const int lane = threadIdx.x & 63;
  const int lrow = lane >> 3;
  const int cgs  = (lane & 7) ^ lrow;

  int Rst[4];
#pragma unroll
  for (int q = 0; q < 4; ++q) Rst[q] = (q * 4 + wave) * 8 + lrow;

  const __bf16* pB[4];
#pragma unroll
  for (int q = 0; q < 4; ++q)
    pB[q] = w2t + ((size_t)e * EMB + nT * 128 + Rst[q]) * HID + cgs * 8;

  const int wm = (wave & 1) * 64;
  const int wn = (wave >> 1) * 64;
  const int fr = lane & 15;
  const int fc = lane >> 4;
  int aOff0[4], aOff1[4], bOff0[4], bOff1[4];
#pragma unroll
  for (int i = 0; i < 4; ++i) {
    int R = wm + i * 16 + fr;
    aOff0[i] = R * 128 + (((fc)     ^ (R & 7)) << 4);
    aOff1[i] = R * 128 + (((fc + 4) ^ (R & 7)) << 4);
  }
#pragma unroll
  for (int j = 0; j < 4; ++j) {
    int R = wn + j * 16 + fr;
    bOff0[j] = R * 128 + (((fc)     ^ (R & 7)) << 4);
    bOff1[j] = R * 128 + (((fc + 4) ^ (R & 7)) << 4);
  }

  const int colBase = nT * 128 + wn + fr;
  float bv[4];
#pragma unroll
  for (int j = 0; j < 4; ++j) bv[j] = eload(b2, (size_t)e * EMB + colBase + j * 16, b2f32);

  for (int mT = g; mT * 128 < cnt; mT += 16) {
    const int rowBase = offsets[e] + mT * 128;
    const __bf16* pA[4];
#pragma unroll
    for (int q = 0; q < 4; ++q)
      pA[q] = hbuf + (size_t)(rowBase + Rst[q]) * HID + cgs * 8;

    floatx4 acc[4][4];
#pragma unroll
    for (int i = 0; i < 4; ++i)
#pragma unroll
      for (int j = 0; j < 4; ++j) acc[i][j] = (floatx4){0.f, 0.f, 0.f, 0.f};

    for (int kb = 0; kb < HID / 64; ++kb) {
      __syncthreads();
#pragma unroll
      for (int q = 0; q < 4; ++q) glds16(pA[q] + (size_t)kb * 64, As + (q * 4 + wave) * 512);
#pragma unroll
      for (int q = 0; q < 4; ++q) glds16(pB[q] + (size_t)kb * 64, Bs + (q * 4 + wave) * 512);
      __syncthreads();
      bf16x8 af[4], bfr[4];
#pragma unroll
      for (int i = 0; i < 4; ++i) af[i]  = *(const bf16x8*)((const char*)As + aOff0[i]);
#pragma unroll
      for (int j = 0; j < 4; ++j) bfr[j] = *(const bf16x8*)((const char*)Bs + bOff0[j]);
#pragma unroll
      for (int i = 0; i < 4; ++i)
#pragma unroll
        for (int j = 0; j < 4; ++j)
          acc[i][j] = __builtin_amdgcn_mfma_f32_16x16x32_bf16(af[i], bfr[j], acc[i][j], 0, 0, 0);
#pragma unroll
      for (int i = 0; i < 4; ++i) af[i]  = *(const bf16x8*)((const char*)As + aOff1[i]);
#pragma unroll
      for (int j = 0; j < 4; ++j) bfr[j] = *(const bf16x8*)((const char*)Bs + bOff1[j]);
#pragma unroll
      for (int i = 0; i < 4; ++i)
#pragma unroll
        for (int j = 0; j < 4; ++j)
          acc[i][j] = __builtin_amdgcn_mfma_f32_16x16x32_bf16(af[i], bfr[j], acc[i][j], 0, 0, 0);
    }

#pragma unroll
    for (int i = 0; i < 4; ++i) {
      const int rowLoc = wm + i * 16 + fc * 4;
#pragma unroll
      for (int r = 0; r < 4; ++r) {
        const int row = rowLoc + r;
        if (mT * 128 + row < cnt) {
          __bf16* yp = ybuf + (size_t)(rowBase + row) * EMB + colBase;
#pragma unroll
          for (int j = 0; j < 4; ++j)
            yp[j * 16] = (__bf16)(acc[i][j][r] + bv[j]);
        }
      }
    }
  }
}

// ---------------- combine: out[t] = (sum_s ybuf[offsets[e]+pos]) / k ----------------
__global__ __launch_bounds__(256)
void combine_kernel(const __bf16* __restrict__ ybuf, const int* __restrict__ tokmap,
                    const int* __restrict__ offsets, const int* __restrict__ kptr,
                    const void* __restrict__ x, void* __restrict__ out) {
  const bool f32 = wave_sniff_f32(x, T_TOK * EMB);   // out dtype == x dtype
  const int wave = threadIdx.x >> 6;
  const int lane = threadIdx.x & 63;
  const int t = blockIdx.x * 4 + wave;
  int k = kptr[0];
  if (k < 1) k = 1; if (k > NE) k = NE;
  const float invk = 1.0f / (float)k;
  int rows[NE];
  for (int s = 0; s < k; ++s) {
    int m = tokmap[t * 8 + s];
    rows[s] = offsets[(m >> 16) & 7] + (m & 0xFFFF);
  }
#pragma unroll
  for (int c = 0; c < 2; ++c) {
    const int i = c * 512 + lane * 8;
    float a[8];
#pragma unroll
    for (int j = 0; j < 8; ++j) a[j] = 0.f;
    for (int s = 0; s < k; ++s) {
      bf16x8 y = *(const bf16x8*)(ybuf + (size_t)rows[s] * EMB + i);
#pragma unroll
      for (int j = 0; j < 8; ++j) a[j] += (float)y[j];
    }
    if (f32) {
      float* op = (float*)out + (size_t)t * EMB + i;
      float4 u = {a[0] * invk, a[1] * invk, a[2] * invk, a[3] * invk};
      float4 v = {a[4] * invk, a[5] * invk, a[6] * invk, a[7] * invk};
      *(float4*)op = u;
      *(float4*)(op + 4) = v;
    } else {
      bf16x8 o;
#pragma unroll
      for (int j = 0; j < 8; ++j) o[j] = (__bf16)(a[j] * invk);
      *(bf16x8*)((__bf16*)out + (size_t)t * EMB + i) = o;
    }
  }
}

extern "C" void kernel_launch(void* const* d_in, const int* in_sizes, int n_in,
                              void* d_out, int out_size, void* d_ws, size_t ws_size,
                              hipStream_t stream) {
  (void)in_sizes; (void)n_in; (void)out_size;
  if (ws_size < (size_t)WS_NEEDED) return;

  const void* x  = d_in[0];
  const void* Wr = d_in[1];
  const void* br = d_in[2];
  const void* W1 = d_in[3];
  const void* b1 = d_in[4];
  const void* W2 = d_in[5];
  const void* b2 = d_in[6];
  const int* kptr = (const int*)d_in[7];

  char* ws = (char*)d_ws;
  int*    counts   = (int*)(ws + WS_COUNTS);
  int*    offsets  = (int*)(ws + WS_OFFSETS);
  int*    tokmap   = (int*)(ws + WS_TOKMAP);
  int*    tok_list = (int*)(ws + WS_TOKLIST);
  __bf16* ybuf     = (__bf16*)(ws + WS_YBUF);
  __bf16* xbf      = (__bf16*)(ws + WS_YBUF);   // aliases ybuf; dead before gemm2 writes
  __bf16* w1t      = (__bf16*)(ws + WS_W1T);
  __bf16* w2t      = (__bf16*)(ws + WS_W2T);
  __bf16* hbuf     = (__bf16*)(ws + WS_H);

  prep_kernel<<<dim3(1536 + T_TOK / 4), 256, 0, stream>>>(
      W1, W2, w1t, w2t, x, Wr, br, kptr, tokmap, xbf);

  bin_kernel<<<dim3(1), 1024, 0, stream>>>(kptr, tokmap, tok_list, counts, offsets);

  gemm1_kernel<<<dim3(8 * 16 * 12), 256, 0, stream>>>(
      xbf, w1t, b1, counts, offsets, tok_list, hbuf);
  gemm2_kernel<<<dim3(8 * 16 * 8), 256, 0, stream>>>(
      hbuf, w2t, b2, counts, offsets, ybuf);

  combine_kernel<<<dim3(T_TOK / 4), 256, 0, stream>>>(ybuf, tokmap, offsets, kptr, x, d_out);
}

// Round 15
// 370.827 us; speedup vs baseline: 1.3804x; 1.0204x over previous
//
#include <hip/hip_runtime.h>
#include <hip/hip_bf16.h>
#include <math.h>

#define T_TOK 8192
#define EMB   1024
#define HID   1536
#define NE    8

typedef float  floatx4 __attribute__((ext_vector_type(4)));
typedef __bf16 bf16x8  __attribute__((ext_vector_type(8)));

// ---- workspace layout (bytes) ----
#define WS_COUNTS   0
#define WS_OFFSETS  1024
#define WS_TOKMAP   8192        // T*8*4
#define WS_TOKLIST  270336      // NE*T*4
#define WS_YBUF     532480      // ybuf 16384*1024*2; xbf aliases it (dead before gemm2 writes)
#define WS_W1T      34086912    // 25165824
#define WS_W2T      59252736    // 25165824
#define WS_H        84418560    // hbuf 16512 rows * 1536 * 2 (128-row pad for tail tiles)
#define WS_NEEDED   135143424

// wave-level dtype sniff (256-word cap; all waves compute the same answer).
__device__ __forceinline__ bool wave_sniff_f32(const void* p, int nelem) {
  const unsigned* w = (const unsigned*)p;
  int nw = nelem >> 1; if (nw > 256) nw = 256;
  const int lane = threadIdx.x & 63;
  int pl = 0, nz = 0;
  for (int i = lane; i < nw; i += 64) {
    unsigned v = w[i];
    if (v) { nz++; unsigned ex = (v >> 23) & 255; if (ex >= 100 && ex <= 150) pl++; }
  }
#pragma unroll
  for (int off = 32; off; off >>= 1) { pl += __shfl_xor(pl, off, 64); nz += __shfl_xor(nz, off, 64); }
  return 2 * pl > nz;
}

__device__ __forceinline__ float eload(const void* p, size_t idx, bool f32) {
  return f32 ? ((const float*)p)[idx] : (float)(((const __bf16*)p)[idx]);
}

// async global->LDS, 16B per lane; LDS dest = wave-uniform base + lane*16
__device__ __forceinline__ void glds16(const void* g, void* l) {
  __builtin_amdgcn_global_load_lds(
      (const __attribute__((address_space(1))) unsigned int*)g,
      (__attribute__((address_space(3))) unsigned int*)l, 16, 0, 0);
}

// register 8x8 micro-tile transpose of one 64x64 tile per wave (r11 structure)
__device__ __forceinline__ void transpose_tile(const void* in, __bf16* out,
                                               int K, int N, bool f32,
                                               int t, int lane) {
  const int ntile = N / 64;
  const int e  = t / 384;                 // 384 tiles/expert for both W1,W2
  const int r  = t % 384;
  const int kb = r / ntile;
  const int nb = r % ntile;
  const size_t eoff = (size_t)e * (size_t)K * (size_t)N;
  const int k0 = kb * 64 + (lane >> 3) * 8;
  const int n0 = nb * 64 + (lane & 7) * 8;

  if (f32) {
    floatx4 a0[8], a1[8];
#pragma unroll
    for (int i = 0; i < 8; ++i) {
      const float* g = (const float*)in + eoff + (size_t)(k0 + i) * N + n0;
      a0[i] = *(const floatx4*)g;
      a1[i] = *(const floatx4*)(g + 4);
    }
#pragma unroll
    for (int j = 0; j < 8; ++j) {
      bf16x8 o;
#pragma unroll
      for (int i = 0; i < 8; ++i)
        o[i] = (__bf16)(j < 4 ? a0[i][j] : a1[i][j - 4]);
      *(bf16x8*)(out + eoff + (size_t)(n0 + j) * K + k0) = o;
    }
  } else {
    bf16x8 a[8];
#pragma unroll
    for (int i = 0; i < 8; ++i)
      a[i] = *(const bf16x8*)((const __bf16*)in + eoff + (size_t)(k0 + i) * N + n0);
#pragma unroll
    for (int j = 0; j < 8; ++j) {
      bf16x8 o;
#pragma unroll
      for (int i = 0; i < 8; ++i) o[i] = a[i][j];
      *(bf16x8*)(out + eoff + (size_t)(n0 + j) * K + k0) = o;
    }
  }
}

// =====================================================================
// prep_kernel: W1 transpose + logits/top-k/x->bf16. W2's transpose has
// MOVED into gemm1's grid (gemm1 doesn't read w2t; the kernel boundary
// before gemm2 guarantees completeness) so it overlaps gemm1's idle BW.
// blocks [0,768): W1 [E][H]->w1t (4 tiles/block, 1/wave)
// blocks [768,2816): logits for 4 tokens each; tokmap slots = expert ids
// =====================================================================
__global__ __launch_bounds__(256)
void prep_kernel(const void* __restrict__ W1, __bf16* __restrict__ w1t,
                 const void* __restrict__ x, const void* __restrict__ Wr,
                 const void* __restrict__ br, const int* __restrict__ kptr,
                 int* __restrict__ tokmap, __bf16* __restrict__ xbf) {
  const int bid = blockIdx.x;
  const int tid = threadIdx.x;
  const int wave = tid >> 6;
  const int lane = tid & 63;

  if (bid < 768) {
    const bool f32 = wave_sniff_f32(W1, NE * EMB * HID);
    transpose_tile(W1, w1t, EMB, HID, f32, bid * 4 + wave, lane);
    return;
  }

  // ---- logits role ----
  const bool xf32  = wave_sniff_f32(x, T_TOK * EMB);
  const bool wrf32 = wave_sniff_f32(Wr, EMB * NE);
  const bool brf32 = wave_sniff_f32(br, NE);
  const int t = (bid - 768) * 4 + wave;

  float xv[16];
  {
    size_t base = (size_t)t * EMB + lane * 16;
    if (xf32) {
      const float* g = (const float*)x + base;
#pragma unroll
      for (int c = 0; c < 4; ++c) {
        float4 v = *(const float4*)(g + c * 4);
        xv[c * 4 + 0] = v.x; xv[c * 4 + 1] = v.y; xv[c * 4 + 2] = v.z; xv[c * 4 + 3] = v.w;
      }
    } else {
      bf16x8 u = *(const bf16x8*)((const __bf16*)x + base);
      bf16x8 v = *(const bf16x8*)((const __bf16*)x + base + 8);
#pragma unroll
      for (int j = 0; j < 8; ++j) { xv[j] = (float)u[j]; xv[8 + j] = (float)v[j]; }
    }
  }
  {
    bf16x8 o0, o1;
#pragma unroll
    for (int j = 0; j < 8; ++j) { o0[j] = (__bf16)xv[j]; o1[j] = (__bf16)xv[8 + j]; }
    __bf16* xo = xbf + (size_t)t * EMB + lane * 16;
    *(bf16x8*)xo = o0;
    *(bf16x8*)(xo + 8) = o1;
  }
  float acc[NE];
#pragma unroll
  for (int e = 0; e < NE; ++e) acc[e] = 0.f;
  if (wrf32) {
#pragma unroll
    for (int j = 0; j < 16; ++j) {
      const float* wr = (const float*)Wr + (size_t)(lane * 16 + j) * NE;
#pragma unroll
      for (int e = 0; e < NE; ++e) acc[e] += xv[j] * wr[e];
    }
  } else {
#pragma unroll
    for (int j = 0; j < 16; ++j) {
      bf16x8 wr = *(const bf16x8*)((const __bf16*)Wr + (size_t)(lane * 16 + j) * NE);
#pragma unroll
      for (int e = 0; e < NE; ++e) acc[e] += xv[j] * (float)wr[e];
    }
  }
#pragma unroll
  for (int e = 0; e < NE; ++e) {
#pragma unroll
    for (int off = 32; off > 0; off >>= 1)
      acc[e] += __shfl_xor(acc[e], off, 64);
  }
  if (lane == 0) {
    int k = kptr[0];
    if (k < 1) k = 1; if (k > NE) k = NE;
    float lg[NE];
#pragma unroll
    for (int e = 0; e < NE; ++e) lg[e] = acc[e] + eload(br, e, brf32);
    for (int s = 0; s < k; ++s) {
      int bi = 0; float bv = lg[0];
#pragma unroll
      for (int e = 1; e < NE; ++e) { if (lg[e] > bv) { bv = lg[e]; bi = e; } }
      lg[bi] = -3.0e38f;
      tokmap[t * 8 + s] = bi;
    }
  }
}

// =====================================================================
// bin_kernel: single block, 1024 threads, LDS atomics (measured ~10us).
// =====================================================================
__global__ __launch_bounds__(1024)
void bin_kernel(const int* __restrict__ kptr, int* __restrict__ tokmap,
                int* __restrict__ tok_list, int* __restrict__ counts,
                int* __restrict__ offsets) {
  __shared__ int lcnt[NE];
  __shared__ int soff[NE + 1];
  const int tid = threadIdx.x;
  if (tid < NE) lcnt[tid] = 0;
  __syncthreads();
  int k = kptr[0];
  if (k < 1) k = 1; if (k > NE) k = NE;
  for (int t = tid; t < T_TOK; t += 1024) {
    for (int s = 0; s < k; ++s) {
      int e = tokmap[t * 8 + s] & 7;
      int pos = atomicAdd(&lcnt[e], 1);
      tok_list[e * T_TOK + pos] = t;
      tokmap[t * 8 + s] = (e << 16) | pos;
    }
  }
  __syncthreads();
  if (tid == 0) {
    int s = 0;
    for (int e = 0; e < NE; ++e) { soff[e] = s; s += lcnt[e]; }
    soff[NE] = s;
  }
  __syncthreads();
  if (tid < NE) counts[tid] = lcnt[tid];
  if (tid <= NE) offsets[tid] = soff[tid];
  for (int e = 0; e < NE; ++e) {
    const int c = lcnt[e];
    const int end = (c + 127) & ~127;
    for (int i = c + tid; i < end; i += 1024) tok_list[e * T_TOK + i] = 0;
  }
}

// =====================================================================
// GEMM1 (+ co-scheduled W2 transpose): blocks [0,768) transpose W2 into
// w2t (overlapping gemm1's idle memory pipe; w2t consumed only by gemm2,
// whose launch boundary guarantees completeness). Blocks [768,2304) run
// the m97-structure BK=64 grouped GEMM (K-loop byte-identical to r8-r14).
// =====================================================================
__global__ __launch_bounds__(256, 4)
void gemm1_kernel(const __bf16* __restrict__ xbf, const __bf16* __restrict__ w1t,
                  const void* __restrict__ b1, const int* __restrict__ counts,
                  const int* __restrict__ offsets, const int* __restrict__ tok_list,
                  __bf16* __restrict__ hbuf,
                  const void* __restrict__ W2, __bf16* __restrict__ w2t) {
  const int bid = blockIdx.x;
  const int lane = threadIdx.x & 63;

  if (bid < 768) {
    const bool f32 = wave_sniff_f32(W2, NE * EMB * HID);
    transpose_tile(W2, w2t, HID, EMB, f32, bid * 4 + (threadIdx.x >> 6), lane);
    return;
  }

  const int flat = bid - 768;
  const int e   = flat & 7;              // expert -> XCD pin
  const int idx = flat >> 3;             // 0..191
  const int g   = idx / 12;              // 0..15 (mT stride group)
  const int nT  = idx % 12;              // 0..11
  const int cnt = counts[e];
  const bool b1f32 = wave_sniff_f32(b1, NE * HID);

  __shared__ __align__(16) __bf16 As[128 * 64];
  __shared__ __align__(16) __bf16 Bs[128 * 64];

  const int wave = threadIdx.x >> 6;
  const int lrow = lane >> 3;            // 0..7
  const int cgs  = (lane & 7) ^ lrow;    // swizzled source chunk

  int Rst[4];
#pragma unroll
  for (int q = 0; q < 4; ++q) Rst[q] = (q * 4 + wave) * 8 + lrow;

  const __bf16* pB[4];
#pragma unroll
  for (int q = 0; q < 4; ++q)
    pB[q] = w1t + ((size_t)e * HID + nT * 128 + Rst[q]) * EMB + cgs * 8;

  const int wm = (wave & 1) * 64;
  const int wn = (wave >> 1) * 64;
  const int fr = lane & 15;
  const int fc = lane >> 4;
  int aOff0[4], aOff1[4], bOff0[4], bOff1[4];
#pragma unroll
  for (int i = 0; i < 4; ++i) {
    int R = wm + i * 16 + fr;
    aOff0[i] = R * 128 + (((fc)     ^ (R & 7)) << 4);
    aOff1[i] = R * 128 + (((fc + 4) ^ (R & 7)) << 4);
  }
#pragma unroll
  for (int j = 0; j < 4; ++j) {
    int R = wn + j * 16 + fr;
    bOff0[j] = R * 128 + (((fc)     ^ (R & 7)) << 4);
    bOff1[j] = R * 128 + (((fc + 4) ^ (R & 7)) << 4);
  }

  const int colBase = nT * 128 + wn + fr;
  float bv[4];
#pragma unroll
  for (int j = 0; j < 4; ++j) bv[j] = eload(b1, (size_t)e * HID + colBase + j * 16, b1f32);

  for (int mT = g; mT * 128 < cnt; mT += 16) {
    const __bf16* pA[4];
#pragma unroll
    for (int q = 0; q < 4; ++q) {
      const int tok = tok_list[e * T_TOK + mT * 128 + Rst[q]];  // pad entries = 0
      pA[q] = xbf + (size_t)tok * EMB + cgs * 8;
    }

    floatx4 acc[4][4];
#pragma unroll
    for (int i = 0; i < 4; ++i)
#pragma unroll
      for (int j = 0; j < 4; ++j) acc[i][j] = (floatx4){0.f, 0.f, 0.f, 0.f};

    for (int kb = 0; kb < EMB / 64; ++kb) {
      __syncthreads();
#pragma unroll
      for (int q = 0; q < 4; ++q) glds16(pA[q] + (size_t)kb * 64, As + (q * 4 + wave) * 512);
#pragma unroll
      for (int q = 0; q < 4; ++q) glds16(pB[q] + (size_t)kb * 64, Bs + (q * 4 + wave) * 512);
      __syncthreads();
      bf16x8 af[4], bfr[4];
#pragma unroll
      for (int i = 0; i < 4; ++i) af[i]  = *(const bf16x8*)((const char*)As + aOff0[i]);
#pragma unroll
      for (int j = 0; j < 4; ++j) bfr[j] = *(const bf16x8*)((const char*)Bs + bOff0[j]);
#pragma unroll
      for (int i = 0; i < 4; ++i)
#pragma unroll
        for (int j = 0; j < 4; ++j)
          acc[i][j] = __builtin_amdgcn_mfma_f32_16x16x32_bf16(af[i], bfr[j], acc[i][j], 0, 0, 0);
#pragma unroll
      for (int i = 0; i < 4; ++i) af[i]  = *(const bf16x8*)((const char*)As + aOff1[i]);
#pragma unroll
      for (int j = 0; j < 4; ++j) bfr[j] = *(const bf16x8*)((const char*)Bs + bOff1[j]);
#pragma unroll
      for (int i = 0; i < 4; ++i)
#pragma unroll
        for (int j = 0; j < 4; ++j)
          acc[i][j] = __builtin_amdgcn_mfma_f32_16x16x32_bf16(af[i], bfr[j], acc[i][j], 0, 0, 0);
    }

    const int hBase = offsets[e] + mT * 128;
#pragma unroll
    for (int i = 0; i < 4; ++i) {
      const int rowLoc = wm + i * 16 + fc * 4;
#pragma unroll
      for (int r = 0; r < 4; ++r) {
        const int row = rowLoc + r;
        if (mT * 128 + row < cnt) {
          __bf16* hp = hbuf + (size_t)(hBase + row) * HID + colBase;
#pragma unroll
          for (int j = 0; j < 4; ++j) {
            float v = acc[i][j][r] + bv[j];
            float gl = 0.5f * v * (1.0f + erff(v * 0.70710678118654752f));
            hp[j * 16] = (__bf16)gl;
          }
        }
      }
    }
  }
}

// ---------------- GEMM2: ybuf[row] = h @ W2[e] + b2[e] ----------------
__global__ __launch_bounds__(256, 4)
void gemm2_kernel(const __bf16* __restrict__ hbuf, const __bf16* __restrict__ w2t,
                  const void* __restrict__ b2, const int* __restrict__ counts,
                  const int* __restrict__ offsets, __bf16* __restrict__ ybuf) {
  const int flat = blockIdx.x;
  const int e   = flat & 7;
  const int idx = flat >> 3;             // 0..127
  const int g   = idx >> 3;              // 0..15
  const int nT  = idx & 7;               // 0..7
  const int cnt = counts[e];
  const bool b2f32 = wave_sniff_f32(b2, NE * EMB);

  __shared__ __align__(16) __bf16 As[128 * 64];
  __shared__ __align__(16) __bf16 Bs[128 * 64];

  const int wave = threadIdx.x >> 6;
  const int lane = threadIdx.x & 63;
  const int lrow = lane >> 3;
  const int cgs  = (lane & 7) ^ lrow;

  int Rst[4];
#pragma unroll
  for (int q = 0; q < 4; ++q) Rst[q] = (q * 4 + wave) * 8 + lrow;

  const __bf16* pB[4];
#pragma unroll
  for (int q = 0; q < 4; ++q)
    pB[q] = w2t + ((size_t)e * EMB + nT * 128 + Rst[q]) * HID + cgs * 8;

  const int wm = (wave & 1) * 64;
  const int wn = (wave >> 1) * 64;
  const int fr = lane & 15;
  const int fc = lane >> 4;
  int aOff0[4], aOff1[4], bOff0[4], bOff1[4];
#pragma unroll
  for (int i = 0; i < 4; ++i) {
    int R = wm + i * 16 + fr;
    aOff0[i] = R * 128 + (((fc)     ^ (R & 7)) << 4);
    aOff1[i] = R * 128 + (((fc + 4) ^ (R & 7)) << 4);
  }
#pragma unroll
  for (int j = 0; j < 4; ++j) {
    int R = wn + j * 16 + fr;
    bOff0[j] = R * 128 + (((fc)     ^ (R & 7)) << 4);
    bOff1[j] = R * 128 + (((fc + 4) ^ (R & 7)) << 4);
  }

  const int colBase = nT * 128 + wn + fr;
  float bv[4];
#pragma unroll
  for (int j = 0; j < 4; ++j) bv[j] = eload(b2, (size_t)e * EMB + colBase + j * 16, b2f32);

  for (int mT = g; mT * 128 < cnt; mT += 16) {
    const int rowBase = offsets[e] + mT * 128;
    const __bf16* pA[4];
#pragma unroll
    for (int q = 0; q < 4; ++q)
      pA[q] = hbuf + (size_t)(rowBase + Rst[q]) * HID + cgs * 8;

    floatx4 acc[4][4];
#pragma unroll
    for (int i = 0; i < 4; ++i)
#pragma unroll
      for (int j = 0; j < 4; ++j) acc[i][j] = (floatx4){0.f, 0.f, 0.f, 0.f};

    for (int kb = 0; kb < HID / 64; ++kb) {
      __syncthreads();
#pragma unroll
      for (int q = 0; q < 4; ++q) glds16(pA[q] + (size_t)kb * 64, As + (q * 4 + wave) * 512);
#pragma unroll
      for (int q = 0; q < 4; ++q) glds16(pB[q] + (size_t)kb * 64, Bs + (q * 4 + wave) * 512);
      __syncthreads();
      bf16x8 af[4], bfr[4];
#pragma unroll
      for (int i = 0; i < 4; ++i) af[i]  = *(const bf16x8*)((const char*)As + aOff0[i]);
#pragma unroll
      for (int j = 0; j < 4; ++j) bfr[j] = *(const bf16x8*)((const char*)Bs + bOff0[j]);
#pragma unroll
      for (int i = 0; i < 4; ++i)
#pragma unroll
        for (int j = 0; j < 4; ++j)
          acc[i][j] = __builtin_amdgcn_mfma_f32_16x16x32_bf16(af[i], bfr[j], acc[i][j], 0, 0, 0);
#pragma unroll
      for (int i = 0; i < 4; ++i) af[i]  = *(const bf16x8*)((const char*)As + aOff1[i]);
#pragma unroll
      for (int j = 0; j < 4; ++j) bfr[j] = *(const bf16x8*)((const char*)Bs + bOff1[j]);
#pragma unroll
      for (int i = 0; i < 4; ++i)
#pragma unroll
        for (int j = 0; j < 4; ++j)
          acc[i][j] = __builtin_amdgcn_mfma_f32_16x16x32_bf16(af[i], bfr[j], acc[i][j], 0, 0, 0);
    }

#pragma unroll
    for (int i = 0; i < 4; ++i) {
      const int rowLoc = wm + i * 16 + fc * 4;
#pragma unroll
      for (int r = 0; r < 4; ++r) {
        const int row = rowLoc + r;
        if (mT * 128 + row < cnt) {
          __bf16* yp = ybuf + (size_t)(rowBase + row) * EMB + colBase;
#pragma unroll
          for (int j = 0; j < 4; ++j)
            yp[j * 16] = (__bf16)(acc[i][j][r] + bv[j]);
        }
      }
    }
  }
}

// ---------------- combine: out[t] = (sum_s ybuf[offsets[e]+pos]) / k ----------------
__global__ __launch_bounds__(256)
void combine_kernel(const __bf16* __restrict__ ybuf, const int* __restrict__ tokmap,
                    const int* __restrict__ offsets, const int* __restrict__ kptr,
                    const void* __restrict__ x, void* __restrict__ out) {
  const bool f32 = wave_sniff_f32(x, T_TOK * EMB);   // out dtype == x dtype
  const int wave = threadIdx.x >> 6;
  const int lane = threadIdx.x & 63;
  const int t = blockIdx.x * 4 + wave;
  int k = kptr[0];
  if (k < 1) k = 1; if (k > NE) k = NE;
  const float invk = 1.0f / (float)k;
  int rows[NE];
  for (int s = 0; s < k; ++s) {
    int m = tokmap[t * 8 + s];
    rows[s] = offsets[(m >> 16) & 7] + (m & 0xFFFF);
  }
#pragma unroll
  for (int c = 0; c < 2; ++c) {
    const int i = c * 512 + lane * 8;
    float a[8];
#pragma unroll
    for (int j = 0; j < 8; ++j) a[j] = 0.f;
    for (int s = 0; s < k; ++s) {
      bf16x8 y = *(const bf16x8*)(ybuf + (size_t)rows[s] * EMB + i);
#pragma unroll
      for (int j = 0; j < 8; ++j) a[j] += (float)y[j];
    }
    if (f32) {
      float* op = (float*)out + (size_t)t * EMB + i;
      float4 u = {a[0] * invk, a[1] * invk, a[2] * invk, a[3] * invk};
      float4 v = {a[4] * invk, a[5] * invk, a[6] * invk, a[7] * invk};
      *(float4*)op = u;
      *(float4*)(op + 4) = v;
    } else {
      bf16x8 o;
#pragma unroll
      for (int j = 0; j < 8; ++j) o[j] = (__bf16)(a[j] * invk);
      *(bf16x8*)((__bf16*)out + (size_t)t * EMB + i) = o;
    }
  }
}

extern "C" void kernel_launch(void* const* d_in, const int* in_sizes, int n_in,
                              void* d_out, int out_size, void* d_ws, size_t ws_size,
                              hipStream_t stream) {
  (void)in_sizes; (void)n_in; (void)out_size;
  if (ws_size < (size_t)WS_NEEDED) return;

  const void* x  = d_in[0];
  const void* Wr = d_in[1];
  const void* br = d_in[2];
  const void* W1 = d_in[3];
  const void* b1 = d_in[4];
  const void* W2 = d_in[5];
  const void* b2 = d_in[6];
  const int* kptr = (const int*)d_in[7];

  char* ws = (char*)d_ws;
  int*    counts   = (int*)(ws + WS_COUNTS);
  int*    offsets  = (int*)(ws + WS_OFFSETS);
  int*    tokmap   = (int*)(ws + WS_TOKMAP);
  int*    tok_list = (int*)(ws + WS_TOKLIST);
  __bf16* ybuf     = (__bf16*)(ws + WS_YBUF);
  __bf16* xbf      = (__bf16*)(ws + WS_YBUF);   // aliases ybuf; dead before gemm2 writes
  __bf16* w1t      = (__bf16*)(ws + WS_W1T);
  __bf16* w2t      = (__bf16*)(ws + WS_W2T);
  __bf16* hbuf     = (__bf16*)(ws + WS_H);

  prep_kernel<<<dim3(768 + T_TOK / 4), 256, 0, stream>>>(
      W1, w1t, x, Wr, br, kptr, tokmap, xbf);

  bin_kernel<<<dim3(1), 1024, 0, stream>>>(kptr, tokmap, tok_list, counts, offsets);

  gemm1_kernel<<<dim3(768 + 8 * 16 * 12), 256, 0, stream>>>(
      xbf, w1t, b1, counts, offsets, tok_list, hbuf, W2, w2t);

  gemm2_kernel<<<dim3(8 * 16 * 8), 256, 0, stream>>>(
      hbuf, w2t, b2, counts, offsets, ybuf);

  combine_kernel<<<dim3(T_TOK / 4), 256, 0, stream>>>(ybuf, tokmap, offsets, kptr, x, d_out);
}